// Round 4
// baseline (832.265 us; speedup 1.0000x reference)
//
#include <hip/hip_runtime.h>

typedef unsigned int uint32;
typedef unsigned short u16;
typedef short s16;
typedef __attribute__((ext_vector_type(8))) s16 s16x8;   // 8 bf16 in 4 VGPRs
typedef __attribute__((ext_vector_type(4))) float fx4;   // MFMA C/D

#define BB 8
#define CC 256
#define TT 4096
#define NN (BB*TT)          // 32768 rows
#define KK 1024
#define RT 16               // rows per block
#define NBLK (NN/RT)        // 2048 blocks
#define BPSZ 262144         // packed B buffer elems

#define OUT_PREC ((size_t)BB*CC*TT)                 // 8388608
#define OUT_PROB (OUT_PREC + 1)                     // 8388609
#define OUT_LOGPROB (OUT_PROB + (size_t)NN*KK)
#define OUT_MEANPROB (OUT_LOGPROB + (size_t)NN*KK)

__device__ __forceinline__ u16 f2bf(float f) {
    uint32 x = __float_as_uint(f);
    x += 0x7fffu + ((x >> 16) & 1u);   // RNE; inputs bounded, no NaN/Inf
    return (u16)(x >> 16);
}
__device__ __forceinline__ float bf2f(u16 h) { return __uint_as_float((uint32)h << 16); }

__device__ __forceinline__ fx4 mfma16(s16x8 a, s16x8 b, fx4 c) {
    return __builtin_amdgcn_mfma_f32_16x16x32_bf16(a, b, c, 0, 0, 0);
}

// -------- one-time prep: enorm, mean_prob zero, precision_q, packed book fragments --------
// bp1h/bp1l[kt*4096 + s*512 + lane*8 + j] = book_bf[kt*16 + (lane&15)][s*32 + (lane>>4)*8 + j]
// bp2h[ct*16384 + s2*512 + lane*8 + j]   = book_bf[s2*32 + (lane>>4)*8 + j][ct*16 + (lane&15)]
__global__ void pack_kernel(const float* __restrict__ book,
                            const float* __restrict__ lpq,
                            float* __restrict__ enorm,
                            u16* __restrict__ bp1h, u16* __restrict__ bp1l,
                            u16* __restrict__ bp2h,
                            float* __restrict__ out) {
    __shared__ float sb[16384];        // 64 KB staging (one-time kernel)
    const int tid = threadIdx.x;
    const int l   = tid & 63;
    const int wv  = tid >> 6;

    if (blockIdx.x < 64) {
        const int kt = blockIdx.x;     // k-tile: book rows kt*16..+15
        for (int i = tid; i < 4096; i += 256) sb[i] = book[(size_t)kt * 4096 + i];
        __syncthreads();
        {
            int row = tid >> 4, l16 = tid & 15;
            float s = 0.f;
#pragma unroll
            for (int i = 0; i < 16; ++i) {
                float v = sb[row * 256 + l16 * 16 + i];
                s = fmaf(v, v, s);
            }
            s += __shfl_xor(s, 1); s += __shfl_xor(s, 2);
            s += __shfl_xor(s, 4); s += __shfl_xor(s, 8);
            if (l16 == 0) enorm[kt * 16 + row] = s;
        }
        if (tid < 16) out[OUT_MEANPROB + kt * 16 + tid] = 0.f;
        if (blockIdx.x == 0 && tid == 0) {
            float pq = 1.f + expf(lpq[0]);
            out[OUT_PREC] = 0.5f / fmaxf(pq, 1e-10f);
        }
#pragma unroll
        for (int si = 0; si < 2; ++si) {
            int s = wv * 2 + si;
            s16x8 vh, vl;
#pragma unroll
            for (int j = 0; j < 8; ++j) {
                float x = sb[(l & 15) * 256 + s * 32 + (l >> 4) * 8 + j];
                u16 hi = f2bf(x);
                vh[j] = (s16)hi;
                vl[j] = (s16)f2bf(x - bf2f(hi));
            }
            *(s16x8*)&bp1h[kt * 4096 + s * 512 + l * 8] = vh;
            *(s16x8*)&bp1l[kt * 4096 + s * 512 + l * 8] = vl;
        }
    } else {
        const int ct = blockIdx.x - 64;  // c-tile: book cols ct*16..+15, all 1024 k
        for (int i = tid; i < 16384; i += 256) {
            int k = i >> 4, c = i & 15;
            sb[i] = book[(size_t)k * 256 + ct * 16 + c];
        }
        __syncthreads();
#pragma unroll
        for (int si = 0; si < 8; ++si) {
            int s2 = wv * 8 + si;
            s16x8 vh;
#pragma unroll
            for (int j = 0; j < 8; ++j) {
                float x = sb[(s2 * 32 + (l >> 4) * 8 + j) * 16 + (l & 15)];
                vh[j] = (s16)f2bf(x);
            }
            *(s16x8*)&bp2h[ct * 16384 + s2 * 512 + l * 8] = vh;
        }
    }
}

// -------- main fused kernel (MFMA) --------
// Fragment layouts (mfma_f32_16x16x32_bf16):
//   A: row = lane&15, k = (lane>>4)*8 + j ; B: col = lane&15, k = (lane>>4)*8 + j
//   D: col = lane&15, row = (lane>>4)*4 + reg    [measured: learn_hip m89]
// LDS A-tiles XOR-swizzled: elem_idx ^= (row&7)<<3 (16B-granular, G4/T2).
// One 32 KB LDS pool aliased across phases: {zh,zl} -> enc_s -> zq_s
// (lifetimes disjoint, separated by barriers) => 33 KB total => 4 blocks/CU.
__global__ __launch_bounds__(256, 4)
void gvq_main(const float* __restrict__ z, const float* __restrict__ lpq,
              const float* __restrict__ u, const float* __restrict__ enorm_g,
              const u16* __restrict__ bp1h, const u16* __restrict__ bp1l,
              const u16* __restrict__ bp2h,
              float* __restrict__ out, float* __restrict__ part) {
    __shared__ u16 pool[RT * KK];      // 32 KB shared pool
    __shared__ float red_s[4][RT];
    __shared__ float znorm_s[RT];

    const int tid  = threadIdx.x;
    const int lane = tid & 63;
    const int w    = tid >> 6;         // wave 0..3
    const int cl   = lane & 15;
    const int h4   = lane >> 4;        // 0..3
    const int n0   = blockIdx.x * RT;  // 4096 % 16 == 0: tile never crosses batch
    const int bb   = n0 / TT;
    const int t0   = n0 % TT;

    const float prec = 0.5f / fmaxf(1.f + __expf(lpq[0]), 1e-10f);

    u16* zh    = pool;                 // [0 .. 4095]   live: phase1 -> GEMM1
    u16* zl    = pool + RT * CC;       // [4096 .. 8191]
    u16* enc_s = pool;                 // [0 .. 16383]  live: softmax2 -> GEMM2
    float* zq_s = (float*)pool;        // 16x257 fp32   live: after GEMM2

    // ---- phase 1: z tile load (thread = channel, 16 t's = 64B), bf16 hi/lo split to LDS
    {
        const float4* zp = (const float4*)(z + ((size_t)bb * CC + tid) * TT + t0);
        float4 a0 = zp[0], a1 = zp[1], a2 = zp[2], a3 = zp[3];
        float zv[16];
        zv[0]=a0.x;  zv[1]=a0.y;  zv[2]=a0.z;  zv[3]=a0.w;
        zv[4]=a1.x;  zv[5]=a1.y;  zv[6]=a1.z;  zv[7]=a1.w;
        zv[8]=a2.x;  zv[9]=a2.y;  zv[10]=a2.z; zv[11]=a2.w;
        zv[12]=a3.x; zv[13]=a3.y; zv[14]=a3.z; zv[15]=a3.w;
#pragma unroll
        for (int r = 0; r < 16; ++r) {
            u16 hi = f2bf(zv[r]);
            u16 lo = f2bf(zv[r] - bf2f(hi));
            int ci = tid ^ ((r & 7) << 3);
            zh[r * CC + ci] = hi;
            zl[r * CC + ci] = lo;
        }
#pragma unroll
        for (int r = 0; r < 16; ++r) {
            float sv = zv[r] * zv[r];
#pragma unroll
            for (int off = 32; off; off >>= 1) sv += __shfl_xor(sv, off);
            if (lane == 0) red_s[w][r] = sv;
        }
    }
    __syncthreads();
    if (tid < RT) znorm_s[tid] = red_s[0][tid] + red_s[1][tid] + red_s[2][tid] + red_s[3][tid];
    __syncthreads();

    // ---- GEMM1 (MFMA, split bf16): wave w owns k-tiles w*16..w*16+15 (cols w*256..+255)
    fx4 acc[16];
    const fx4 fzero = {0.f, 0.f, 0.f, 0.f};
#pragma unroll
    for (int t = 0; t < 16; ++t) acc[t] = fzero;
    {
        const uint32 x5    = (uint32)(cl & 4) << 3;
        const uint32 abase = (uint32)cl * CC + (((uint32)h4 * 8) ^ ((uint32)(cl & 3) << 3));
        const uint32 b1base = (uint32)w * 65536 + (uint32)lane * 8;
#pragma unroll 1
        for (int c0 = 0; c0 < CC; c0 += 32) {
            const uint32 s = (uint32)c0 >> 5;
            s16x8 ah = *(const s16x8*)&zh[abase + ((uint32)c0 ^ x5)];
            s16x8 al = *(const s16x8*)&zl[abase + ((uint32)c0 ^ x5)];
#pragma unroll
            for (int t = 0; t < 16; ++t) {
                s16x8 bh = *(const s16x8*)&bp1h[b1base + t * 4096 + s * 512];
                s16x8 bl = *(const s16x8*)&bp1l[b1base + t * 4096 + s * 512];
                acc[t] = mfma16(ah, bh, acc[t]);
                acc[t] = mfma16(ah, bl, acc[t]);
                acc[t] = mfma16(al, bh, acc[t]);
            }
        }
    }

    // ---- logits = (2*dot - ||z||^2 - ||e||^2) * prec
    float zn[4];
#pragma unroll
    for (int q = 0; q < 4; ++q) zn[q] = znorm_s[h4 * 4 + q];
#pragma unroll
    for (int t = 0; t < 16; ++t) {
        float en = enorm_g[w * 256 + t * 16 + cl];
#pragma unroll
        for (int q = 0; q < 4; ++q)
            acc[t][q] = (2.f * acc[t][q] - zn[q] - en) * prec;
    }

    // ---- softmax 1 (prob / log_prob); row r held by lanes with h4 == r>>2
    float rmax[4], rsum[4];
#pragma unroll
    for (int q = 0; q < 4; ++q) {
        float m = acc[0][q];
#pragma unroll
        for (int t = 1; t < 16; ++t) m = fmaxf(m, acc[t][q]);
        m = fmaxf(m, __shfl_xor(m, 1));
        m = fmaxf(m, __shfl_xor(m, 2));
        m = fmaxf(m, __shfl_xor(m, 4));
        m = fmaxf(m, __shfl_xor(m, 8));
        rmax[q] = m;
    }
    if (cl == 0) {
#pragma unroll
        for (int q = 0; q < 4; ++q) red_s[w][h4 * 4 + q] = rmax[q];
    }
    __syncthreads();
#pragma unroll
    for (int q = 0; q < 4; ++q) {
        int r = h4 * 4 + q;
        rmax[q] = fmaxf(fmaxf(red_s[0][r], red_s[1][r]), fmaxf(red_s[2][r], red_s[3][r]));
    }
    __syncthreads();
#pragma unroll
    for (int q = 0; q < 4; ++q) {
        float sv = 0.f;
#pragma unroll
        for (int t = 0; t < 16; ++t) sv += __expf(acc[t][q] - rmax[q]);
        sv += __shfl_xor(sv, 1); sv += __shfl_xor(sv, 2);
        sv += __shfl_xor(sv, 4); sv += __shfl_xor(sv, 8);
        if (cl == 0) red_s[w][h4 * 4 + q] = sv;
    }
    __syncthreads();
#pragma unroll
    for (int q = 0; q < 4; ++q) {
        int r = h4 * 4 + q;
        rsum[q] = red_s[0][r] + red_s[1][r] + red_s[2][r] + red_s[3][r];
    }

    // ---- fused: prob/log_prob stores + mean_prob partials + u loads + Gumbel
    // (store stream and u-load stream interleave -> MLP in both directions)
    {
        float logs[4];
        size_t rb[4];
#pragma unroll
        for (int q = 0; q < 4; ++q) {
            logs[q] = __logf(rsum[q]);
            rb[q] = (size_t)(n0 + h4 * 4 + q) * KK;
        }
        float* prob_out = out + OUT_PROB;
        float* lp_out   = out + OUT_LOGPROB;
#pragma unroll
        for (int t = 0; t < 16; ++t) {
            int kc = w * 256 + t * 16 + cl;
            float uu[4];
#pragma unroll
            for (int q = 0; q < 4; ++q) uu[q] = u[rb[q] + kc];   // issue loads early
            float mpt = 0.f;
#pragma unroll
            for (int q = 0; q < 4; ++q) {
                float lpv = acc[t][q] - rmax[q] - logs[q];
                float p   = __expf(lpv);
                prob_out[rb[q] + kc] = p;
                lp_out[rb[q] + kc]   = lpv;
                mpt += p;
                float g = -__logf(-__logf(uu[q] + 1e-10f) + 1e-10f);
                acc[t][q] = (acc[t][q] + g) * 2.0f;   // temperature 0.5 => *2
            }
            mpt += __shfl_xor(mpt, 16);   // combine 4 row-groups -> column sum
            mpt += __shfl_xor(mpt, 32);
            if (h4 == 0) {
                if (part) part[(size_t)blockIdx.x * KK + kc] = mpt;
                else atomicAdd(out + OUT_MEANPROB + kc, mpt * (1.f / NN));
            }
        }
    }

    // ---- softmax 2 (encodings)
    __syncthreads();   // guard red_s reuse
#pragma unroll
    for (int q = 0; q < 4; ++q) {
        float m = acc[0][q];
#pragma unroll
        for (int t = 1; t < 16; ++t) m = fmaxf(m, acc[t][q]);
        m = fmaxf(m, __shfl_xor(m, 1));
        m = fmaxf(m, __shfl_xor(m, 2));
        m = fmaxf(m, __shfl_xor(m, 4));
        m = fmaxf(m, __shfl_xor(m, 8));
        rmax[q] = m;
    }
    if (cl == 0) {
#pragma unroll
        for (int q = 0; q < 4; ++q) red_s[w][h4 * 4 + q] = rmax[q];
    }
    __syncthreads();
#pragma unroll
    for (int q = 0; q < 4; ++q) {
        int r = h4 * 4 + q;
        rmax[q] = fmaxf(fmaxf(red_s[0][r], red_s[1][r]), fmaxf(red_s[2][r], red_s[3][r]));
    }
    __syncthreads();
#pragma unroll
    for (int q = 0; q < 4; ++q) {
        float sv = 0.f;
#pragma unroll
        for (int t = 0; t < 16; ++t) sv += __expf(acc[t][q] - rmax[q]);
        sv += __shfl_xor(sv, 1); sv += __shfl_xor(sv, 2);
        sv += __shfl_xor(sv, 4); sv += __shfl_xor(sv, 8);
        if (cl == 0) red_s[w][h4 * 4 + q] = sv;
    }
    __syncthreads();
#pragma unroll
    for (int q = 0; q < 4; ++q) {
        int r = h4 * 4 + q;
        rsum[q] = red_s[0][r] + red_s[1][r] + red_s[2][r] + red_s[3][r];
    }

    // prefetch first GEMM2 B-step (global; independent of the coming barrier)
    s16x8 bh0[4];
    {
        const uint32 b2base = (uint32)w * 65536 + (uint32)lane * 8;
#pragma unroll
        for (int ct = 0; ct < 4; ++ct)
            bh0[ct] = *(const s16x8*)&bp2h[b2base + ct * 16384];
    }

    {
        float inv[4];
#pragma unroll
        for (int q = 0; q < 4; ++q) inv[q] = 1.f / rsum[q];
#pragma unroll
        for (int t = 0; t < 16; ++t) {
            int kc = w * 256 + t * 16 + cl;
#pragma unroll
            for (int q = 0; q < 4; ++q) {
                int r = h4 * 4 + q;
                float e = __expf(acc[t][q] - rmax[q]) * inv[q];
                enc_s[r * KK + (kc ^ ((r & 7) << 3))] = f2bf(e);
            }
        }
    }
    __syncthreads();

    // ---- GEMM2 (MFMA, bf16 book): z_q[r][c] = sum_k enc[k]*book[k][c]; wave w owns c-tiles w*4..+3
    fx4 accz[4];
#pragma unroll
    for (int ct = 0; ct < 4; ++ct) accz[ct] = fzero;
    {
        const uint32 x5     = (uint32)(cl & 4) << 3;
        const uint32 a2base = (uint32)cl * KK + (((uint32)h4 * 8) ^ ((uint32)(cl & 3) << 3));
        const uint32 b2base = (uint32)w * 65536 + (uint32)lane * 8;
        // peeled k0 = 0 using prefetched bh0
        {
            s16x8 a = *(const s16x8*)&enc_s[a2base + x5];
#pragma unroll
            for (int ct = 0; ct < 4; ++ct)
                accz[ct] = mfma16(a, bh0[ct], accz[ct]);
        }
#pragma unroll 1
        for (int k0 = 32; k0 < KK; k0 += 32) {
            const uint32 s2 = (uint32)k0 >> 5;
            s16x8 a = *(const s16x8*)&enc_s[a2base + ((uint32)k0 ^ x5)];
#pragma unroll
            for (int ct = 0; ct < 4; ++ct) {
                s16x8 bh = *(const s16x8*)&bp2h[b2base + ct * 16384 + s2 * 512];
                accz[ct] = mfma16(a, bh, accz[ct]);
            }
        }
    }
    __syncthreads();   // all waves done reading enc_s before zq_s alias-write

    // ---- stage z_q tile to LDS ([16][257] pad breaks 4-row write conflict), coalesced store
#pragma unroll
    for (int ct = 0; ct < 4; ++ct) {
        int c = w * 64 + ct * 16 + cl;
#pragma unroll
        for (int q = 0; q < 4; ++q)
            zq_s[(h4 * 4 + q) * 257 + c] = accz[ct][q];
    }
    __syncthreads();
    {
        float4* op = (float4*)(out + ((size_t)bb * CC + tid) * TT + t0);
#pragma unroll
        for (int i = 0; i < 4; ++i)
            op[i] = make_float4(zq_s[(i*4+0)*257 + tid], zq_s[(i*4+1)*257 + tid],
                                zq_s[(i*4+2)*257 + tid], zq_s[(i*4+3)*257 + tid]);
    }
}

// -------- mean_prob reduction over per-block partials --------
__global__ void meanp_kernel(const float* __restrict__ part, float* __restrict__ out) {
    int k  = blockIdx.x * blockDim.x + threadIdx.x;   // 4 x 256 = 1024 k's
    int b0 = blockIdx.y * (NBLK / 64);
    float s = 0.f;
#pragma unroll 4
    for (int b = 0; b < NBLK / 64; ++b)
        s += part[(size_t)(b0 + b) * KK + k];
    atomicAdd(out + OUT_MEANPROB + k, s * (1.f / NN));
}

extern "C" void kernel_launch(void* const* d_in, const int* in_sizes, int n_in,
                              void* d_out, int out_size, void* d_ws, size_t ws_size,
                              hipStream_t stream) {
    const float* z    = (const float*)d_in[0];
    const float* book = (const float*)d_in[1];
    const float* lpq  = (const float*)d_in[2];
    const float* u    = (const float*)d_in[3];
    float* out = (float*)d_out;

    // workspace: enorm(4KB) | bp1h,bp1l,bp2h (3 x 512KB bf16 packed fragments) | part (8MB)
    float* enorm = (float*)d_ws;
    u16* bp1h = (u16*)(enorm + KK);
    u16* bp1l = bp1h + BPSZ;
    u16* bp2h = bp1l + BPSZ;
    float* part = (float*)(bp2h + BPSZ);
    size_t need = (size_t)KK * sizeof(float) + 3 * (size_t)BPSZ * sizeof(u16)
                + (size_t)NBLK * KK * sizeof(float);
    if (ws_size < need) part = nullptr;

    pack_kernel<<<80, 256, 0, stream>>>(book, lpq, enorm, bp1h, bp1l, bp2h, out);
    gvq_main<<<NBLK, 256, 0, stream>>>(z, lpq, u, enorm, bp1h, bp1l, bp2h, out, part);
    if (part != nullptr)
        meanp_kernel<<<dim3(4, 64), 256, 0, stream>>>(part, out);
}

// Round 6
// 667.441 us; speedup vs baseline: 1.2469x; 1.2469x over previous
//
#include <hip/hip_runtime.h>

typedef unsigned int uint32;
typedef unsigned short u16;
typedef short s16;
typedef __attribute__((ext_vector_type(8))) s16 s16x8;   // 8 bf16 in 4 VGPRs
typedef __attribute__((ext_vector_type(4))) float fx4;   // MFMA C/D

#define BB 8
#define CC 256
#define TT 4096
#define NN (BB*TT)          // 32768 rows
#define KK 1024
#define RT 16               // rows per block
#define NBLK (NN/RT)        // 2048 blocks
#define BPSZ 262144         // packed B buffer elems

#define OUT_PREC ((size_t)BB*CC*TT)                 // 8388608
#define OUT_PROB (OUT_PREC + 1)                     // 8388609
#define OUT_LOGPROB (OUT_PROB + (size_t)NN*KK)
#define OUT_MEANPROB (OUT_LOGPROB + (size_t)NN*KK)

__device__ __forceinline__ u16 f2bf(float f) {
    uint32 x = __float_as_uint(f);
    x += 0x7fffu + ((x >> 16) & 1u);   // RNE; inputs bounded, no NaN/Inf
    return (u16)(x >> 16);
}
__device__ __forceinline__ float bf2f(u16 h) { return __uint_as_float((uint32)h << 16); }

__device__ __forceinline__ fx4 mfma16(s16x8 a, s16x8 b, fx4 c) {
    return __builtin_amdgcn_mfma_f32_16x16x32_bf16(a, b, c, 0, 0, 0);
}

// -------- one-time prep: enorm, mean_prob zero, precision_q, packed book fragments --------
// bp1h/bp1l[kt*4096 + s*512 + lane*8 + j] = book_bf[kt*16 + (lane&15)][s*32 + (lane>>4)*8 + j]
// bp2h[ct*16384 + s2*512 + lane*8 + j]   = book_bf[s2*32 + (lane>>4)*8 + j][ct*16 + (lane&15)]
__global__ void pack_kernel(const float* __restrict__ book,
                            const float* __restrict__ lpq,
                            float* __restrict__ enorm,
                            u16* __restrict__ bp1h, u16* __restrict__ bp1l,
                            u16* __restrict__ bp2h,
                            float* __restrict__ out) {
    __shared__ float sb[16384];        // 64 KB staging (one-time kernel)
    const int tid = threadIdx.x;
    const int l   = tid & 63;
    const int wv  = tid >> 6;

    if (blockIdx.x < 64) {
        const int kt = blockIdx.x;     // k-tile: book rows kt*16..+15
        for (int i = tid; i < 4096; i += 256) sb[i] = book[(size_t)kt * 4096 + i];
        __syncthreads();
        {
            int row = tid >> 4, l16 = tid & 15;
            float s = 0.f;
#pragma unroll
            for (int i = 0; i < 16; ++i) {
                float v = sb[row * 256 + l16 * 16 + i];
                s = fmaf(v, v, s);
            }
            s += __shfl_xor(s, 1); s += __shfl_xor(s, 2);
            s += __shfl_xor(s, 4); s += __shfl_xor(s, 8);
            if (l16 == 0) enorm[kt * 16 + row] = s;
        }
        if (tid < 16) out[OUT_MEANPROB + kt * 16 + tid] = 0.f;
        if (blockIdx.x == 0 && tid == 0) {
            float pq = 1.f + expf(lpq[0]);
            out[OUT_PREC] = 0.5f / fmaxf(pq, 1e-10f);
        }
#pragma unroll
        for (int si = 0; si < 2; ++si) {
            int s = wv * 2 + si;
            s16x8 vh, vl;
#pragma unroll
            for (int j = 0; j < 8; ++j) {
                float x = sb[(l & 15) * 256 + s * 32 + (l >> 4) * 8 + j];
                u16 hi = f2bf(x);
                vh[j] = (s16)hi;
                vl[j] = (s16)f2bf(x - bf2f(hi));
            }
            *(s16x8*)&bp1h[kt * 4096 + s * 512 + l * 8] = vh;
            *(s16x8*)&bp1l[kt * 4096 + s * 512 + l * 8] = vl;
        }
    } else {
        const int ct = blockIdx.x - 64;  // c-tile: book cols ct*16..+15, all 1024 k
        for (int i = tid; i < 16384; i += 256) {
            int k = i >> 4, c = i & 15;
            sb[i] = book[(size_t)k * 256 + ct * 16 + c];
        }
        __syncthreads();
#pragma unroll
        for (int si = 0; si < 8; ++si) {
            int s2 = wv * 8 + si;
            s16x8 vh;
#pragma unroll
            for (int j = 0; j < 8; ++j) {
                float x = sb[(s2 * 32 + (l >> 4) * 8 + j) * 16 + (l & 15)];
                vh[j] = (s16)f2bf(x);
            }
            *(s16x8*)&bp2h[ct * 16384 + s2 * 512 + l * 8] = vh;
        }
    }
}

// -------- main fused kernel (MFMA, 512 threads = 8 waves) --------
// Fragment layouts (mfma_f32_16x16x32_bf16):
//   A: row = lane&15, k = (lane>>4)*8 + j ; B: col = lane&15, k = (lane>>4)*8 + j
//   D: col = lane&15, row = (lane>>4)*4 + reg    [measured: learn_hip m89]
// LDS A-tiles XOR-swizzled: elem_idx ^= (row&7)<<3 (16B-granular, G4/T2).
// 8 waves: GEMM1 wave w owns k-tiles w*8..+7 (acc[8] = 32 regs/thread, fits
// the 128 reg/wave cap at 4 waves/EU WITHOUT spilling — round-4 lesson).
// One 32 KB LDS pool aliased: {zh,zl} -> enc_s -> zq_s.
__global__ __launch_bounds__(512, 4)
void gvq_main(const float* __restrict__ z, const float* __restrict__ lpq,
              const float* __restrict__ u, const float* __restrict__ enorm_g,
              const u16* __restrict__ bp1h, const u16* __restrict__ bp1l,
              const u16* __restrict__ bp2h,
              float* __restrict__ out, float* __restrict__ part) {
    __shared__ u16 pool[RT * KK];      // 32 KB shared pool
    __shared__ float red_s[8][RT];
    __shared__ float znorm_s[RT];

    const int tid  = threadIdx.x;
    const int lane = tid & 63;
    const int w    = tid >> 6;         // wave 0..7
    const int cl   = lane & 15;
    const int h4   = lane >> 4;        // 0..3
    const int n0   = blockIdx.x * RT;  // 4096 % 16 == 0: tile never crosses batch
    const int bb   = n0 / TT;
    const int t0   = n0 % TT;

    const float prec = 0.5f / fmaxf(1.f + __expf(lpq[0]), 1e-10f);

    u16* zh    = pool;                 // [0 .. 4095]   live: phase1 -> GEMM1
    u16* zl    = pool + RT * CC;       // [4096 .. 8191]
    u16* enc_s = pool;                 // [0 .. 16383]  live: softmax2 -> GEMM2
    float* zq_s = (float*)pool;        // 16x257 fp32   live: after GEMM2

    // ---- phase 1: z tile load. thread = (channel c, half tg): 8 t's = 32B/lane
    {
        const int c  = tid & 255;
        const int tg = tid >> 8;       // 0: rows 0..7, 1: rows 8..15
        const float4* zp = (const float4*)(z + ((size_t)bb * CC + c) * TT + t0 + tg * 8);
        float4 a0 = zp[0], a1 = zp[1];
        float zv[8];
        zv[0]=a0.x; zv[1]=a0.y; zv[2]=a0.z; zv[3]=a0.w;
        zv[4]=a1.x; zv[5]=a1.y; zv[6]=a1.z; zv[7]=a1.w;
#pragma unroll
        for (int j = 0; j < 8; ++j) {
            int r = tg * 8 + j;        // r&7 == j
            u16 hi = f2bf(zv[j]);
            u16 lo = f2bf(zv[j] - bf2f(hi));
            int ci = c ^ (j << 3);
            zh[r * CC + ci] = hi;
            zl[r * CC + ci] = lo;
        }
        // row norms: wave covers 64 channels; rows tg*8..+7 from waves (tg*4..tg*4+3)
#pragma unroll
        for (int j = 0; j < 8; ++j) {
            float sv = zv[j] * zv[j];
#pragma unroll
            for (int off = 32; off; off >>= 1) sv += __shfl_xor(sv, off);
            if (lane == 0) red_s[w][tg * 8 + j] = sv;
        }
    }
    __syncthreads();
    if (tid < RT) {
        int base = (tid >> 3) * 4;     // rows 0-7 <- waves 0-3, rows 8-15 <- waves 4-7
        znorm_s[tid] = red_s[base][tid] + red_s[base+1][tid] + red_s[base+2][tid] + red_s[base+3][tid];
    }
    __syncthreads();

    // ---- GEMM1 (MFMA, split bf16): wave w owns k-tiles w*8..w*8+7 (cols w*128..+127)
    fx4 acc[8];
    const fx4 fzero = {0.f, 0.f, 0.f, 0.f};
#pragma unroll
    for (int t = 0; t < 8; ++t) acc[t] = fzero;
    {
        const uint32 x5    = (uint32)(cl & 4) << 3;
        const uint32 abase = (uint32)cl * CC + (((uint32)h4 * 8) ^ ((uint32)(cl & 3) << 3));
        const uint32 b1base = (uint32)w * 32768 + (uint32)lane * 8;
#pragma unroll 1
        for (int c0 = 0; c0 < CC; c0 += 32) {
            const uint32 s = (uint32)c0 >> 5;
            s16x8 ah = *(const s16x8*)&zh[abase + ((uint32)c0 ^ x5)];
            s16x8 al = *(const s16x8*)&zl[abase + ((uint32)c0 ^ x5)];
#pragma unroll
            for (int t = 0; t < 8; ++t) {
                s16x8 bh = *(const s16x8*)&bp1h[b1base + t * 4096 + s * 512];
                s16x8 bl = *(const s16x8*)&bp1l[b1base + t * 4096 + s * 512];
                acc[t] = mfma16(ah, bh, acc[t]);
                acc[t] = mfma16(ah, bl, acc[t]);
                acc[t] = mfma16(al, bh, acc[t]);
            }
        }
    }

    // ---- logits = (2*dot - ||z||^2 - ||e||^2) * prec
    float zn[4];
#pragma unroll
    for (int q = 0; q < 4; ++q) zn[q] = znorm_s[h4 * 4 + q];
#pragma unroll
    for (int t = 0; t < 8; ++t) {
        float en = enorm_g[w * 128 + t * 16 + cl];
#pragma unroll
        for (int q = 0; q < 4; ++q)
            acc[t][q] = (2.f * acc[t][q] - zn[q] - en) * prec;
    }

    // ---- softmax 1 (prob / log_prob); row r held by lanes with h4 == r>>2
    float rmax[4], rsum[4];
#pragma unroll
    for (int q = 0; q < 4; ++q) {
        float m = acc[0][q];
#pragma unroll
        for (int t = 1; t < 8; ++t) m = fmaxf(m, acc[t][q]);
        m = fmaxf(m, __shfl_xor(m, 1));
        m = fmaxf(m, __shfl_xor(m, 2));
        m = fmaxf(m, __shfl_xor(m, 4));
        m = fmaxf(m, __shfl_xor(m, 8));
        rmax[q] = m;
    }
    if (cl == 0) {
#pragma unroll
        for (int q = 0; q < 4; ++q) red_s[w][h4 * 4 + q] = rmax[q];
    }
    __syncthreads();
#pragma unroll
    for (int q = 0; q < 4; ++q) {
        int r = h4 * 4 + q;
        float m = fmaxf(fmaxf(red_s[0][r], red_s[1][r]), fmaxf(red_s[2][r], red_s[3][r]));
        m = fmaxf(m, fmaxf(fmaxf(red_s[4][r], red_s[5][r]), fmaxf(red_s[6][r], red_s[7][r])));
        rmax[q] = m;
    }
    __syncthreads();
#pragma unroll
    for (int q = 0; q < 4; ++q) {
        float sv = 0.f;
#pragma unroll
        for (int t = 0; t < 8; ++t) sv += __expf(acc[t][q] - rmax[q]);
        sv += __shfl_xor(sv, 1); sv += __shfl_xor(sv, 2);
        sv += __shfl_xor(sv, 4); sv += __shfl_xor(sv, 8);
        if (cl == 0) red_s[w][h4 * 4 + q] = sv;
    }
    __syncthreads();
#pragma unroll
    for (int q = 0; q < 4; ++q) {
        int r = h4 * 4 + q;
        rsum[q] = (red_s[0][r] + red_s[1][r]) + (red_s[2][r] + red_s[3][r])
                + (red_s[4][r] + red_s[5][r]) + (red_s[6][r] + red_s[7][r]);
    }

    // ---- fused: prob/log_prob stores + mean_prob partials + u loads + Gumbel
    {
        float logs[4];
        size_t rb[4];
#pragma unroll
        for (int q = 0; q < 4; ++q) {
            logs[q] = __logf(rsum[q]);
            rb[q] = (size_t)(n0 + h4 * 4 + q) * KK;
        }
        float* prob_out = out + OUT_PROB;
        float* lp_out   = out + OUT_LOGPROB;
#pragma unroll
        for (int t = 0; t < 8; ++t) {
            int kc = w * 128 + t * 16 + cl;
            float uu[4];
#pragma unroll
            for (int q = 0; q < 4; ++q) uu[q] = u[rb[q] + kc];   // issue loads early
            float mpt = 0.f;
#pragma unroll
            for (int q = 0; q < 4; ++q) {
                float lpv = acc[t][q] - rmax[q] - logs[q];
                float p   = __expf(lpv);
                prob_out[rb[q] + kc] = p;
                lp_out[rb[q] + kc]   = lpv;
                mpt += p;
                float g = -__logf(-__logf(uu[q] + 1e-10f) + 1e-10f);
                acc[t][q] = (acc[t][q] + g) * 2.0f;   // temperature 0.5 => *2
            }
            mpt += __shfl_xor(mpt, 16);   // combine 4 row-groups -> column sum
            mpt += __shfl_xor(mpt, 32);
            if (h4 == 0) {
                if (part) part[(size_t)blockIdx.x * KK + kc] = mpt;
                else atomicAdd(out + OUT_MEANPROB + kc, mpt * (1.f / NN));
            }
        }
    }

    // ---- softmax 2 (encodings)
    __syncthreads();   // guard red_s reuse
#pragma unroll
    for (int q = 0; q < 4; ++q) {
        float m = acc[0][q];
#pragma unroll
        for (int t = 1; t < 8; ++t) m = fmaxf(m, acc[t][q]);
        m = fmaxf(m, __shfl_xor(m, 1));
        m = fmaxf(m, __shfl_xor(m, 2));
        m = fmaxf(m, __shfl_xor(m, 4));
        m = fmaxf(m, __shfl_xor(m, 8));
        rmax[q] = m;
    }
    if (cl == 0) {
#pragma unroll
        for (int q = 0; q < 4; ++q) red_s[w][h4 * 4 + q] = rmax[q];
    }
    __syncthreads();
#pragma unroll
    for (int q = 0; q < 4; ++q) {
        int r = h4 * 4 + q;
        float m = fmaxf(fmaxf(red_s[0][r], red_s[1][r]), fmaxf(red_s[2][r], red_s[3][r]));
        m = fmaxf(m, fmaxf(fmaxf(red_s[4][r], red_s[5][r]), fmaxf(red_s[6][r], red_s[7][r])));
        rmax[q] = m;
    }
    __syncthreads();
#pragma unroll
    for (int q = 0; q < 4; ++q) {
        float sv = 0.f;
#pragma unroll
        for (int t = 0; t < 8; ++t) sv += __expf(acc[t][q] - rmax[q]);
        sv += __shfl_xor(sv, 1); sv += __shfl_xor(sv, 2);
        sv += __shfl_xor(sv, 4); sv += __shfl_xor(sv, 8);
        if (cl == 0) red_s[w][h4 * 4 + q] = sv;
    }
    __syncthreads();
#pragma unroll
    for (int q = 0; q < 4; ++q) {
        int r = h4 * 4 + q;
        rsum[q] = (red_s[0][r] + red_s[1][r]) + (red_s[2][r] + red_s[3][r])
                + (red_s[4][r] + red_s[5][r]) + (red_s[6][r] + red_s[7][r]);
    }

    // prefetch first GEMM2 B-step (global; independent of the coming barrier)
    s16x8 bh0[2];
    {
        const uint32 b2base = (uint32)(w * 2) * 16384 + (uint32)lane * 8;
#pragma unroll
        for (int i = 0; i < 2; ++i)
            bh0[i] = *(const s16x8*)&bp2h[b2base + i * 16384];
    }

    {
        float inv[4];
#pragma unroll
        for (int q = 0; q < 4; ++q) inv[q] = 1.f / rsum[q];
#pragma unroll
        for (int t = 0; t < 8; ++t) {
            int kc = w * 128 + t * 16 + cl;
#pragma unroll
            for (int q = 0; q < 4; ++q) {
                int r = h4 * 4 + q;
                float e = __expf(acc[t][q] - rmax[q]) * inv[q];
                enc_s[r * KK + (kc ^ ((r & 7) << 3))] = f2bf(e);
            }
        }
    }
    __syncthreads();

    // ---- GEMM2 (MFMA, bf16 book): z_q[r][c] = sum_k enc[k]*book[k][c]; wave w owns c-tiles w*2..+1
    fx4 accz[2];
#pragma unroll
    for (int i = 0; i < 2; ++i) accz[i] = fzero;
    {
        const uint32 x5     = (uint32)(cl & 4) << 3;
        const uint32 a2base = (uint32)cl * KK + (((uint32)h4 * 8) ^ ((uint32)(cl & 3) << 3));
        const uint32 b2base = (uint32)(w * 2) * 16384 + (uint32)lane * 8;
        // peeled k0 = 0 using prefetched bh0
        {
            s16x8 a = *(const s16x8*)&enc_s[a2base + x5];
#pragma unroll
            for (int i = 0; i < 2; ++i)
                accz[i] = mfma16(a, bh0[i], accz[i]);
        }
#pragma unroll 1
        for (int k0 = 32; k0 < KK; k0 += 32) {
            const uint32 s2 = (uint32)k0 >> 5;
            s16x8 a = *(const s16x8*)&enc_s[a2base + ((uint32)k0 ^ x5)];
#pragma unroll
            for (int i = 0; i < 2; ++i) {
                s16x8 bh = *(const s16x8*)&bp2h[b2base + i * 16384 + s2 * 512];
                accz[i] = mfma16(a, bh, accz[i]);
            }
        }
    }
    __syncthreads();   // all waves done reading enc_s before zq_s alias-write

    // ---- stage z_q tile to LDS ([16][257] pad breaks write conflicts), coalesced store
#pragma unroll
    for (int i = 0; i < 2; ++i) {
        int c = w * 32 + i * 16 + cl;
#pragma unroll
        for (int q = 0; q < 4; ++q)
            zq_s[(h4 * 4 + q) * 257 + c] = accz[i][q];
    }
    __syncthreads();
    {
        const int c  = tid & 255;
        const int tg = tid >> 8;
        float4* op = (float4*)(out + ((size_t)bb * CC + c) * TT + t0 + tg * 8);
        op[0] = make_float4(zq_s[(tg*8+0)*257 + c], zq_s[(tg*8+1)*257 + c],
                            zq_s[(tg*8+2)*257 + c], zq_s[(tg*8+3)*257 + c]);
        op[1] = make_float4(zq_s[(tg*8+4)*257 + c], zq_s[(tg*8+5)*257 + c],
                            zq_s[(tg*8+6)*257 + c], zq_s[(tg*8+7)*257 + c]);
    }
}

// -------- mean_prob reduction over per-block partials --------
__global__ void meanp_kernel(const float* __restrict__ part, float* __restrict__ out) {
    int k  = blockIdx.x * blockDim.x + threadIdx.x;   // 4 x 256 = 1024 k's
    int b0 = blockIdx.y * (NBLK / 64);
    float s = 0.f;
#pragma unroll 4
    for (int b = 0; b < NBLK / 64; ++b)
        s += part[(size_t)(b0 + b) * KK + k];
    atomicAdd(out + OUT_MEANPROB + k, s * (1.f / NN));
}

extern "C" void kernel_launch(void* const* d_in, const int* in_sizes, int n_in,
                              void* d_out, int out_size, void* d_ws, size_t ws_size,
                              hipStream_t stream) {
    const float* z    = (const float*)d_in[0];
    const float* book = (const float*)d_in[1];
    const float* lpq  = (const float*)d_in[2];
    const float* u    = (const float*)d_in[3];
    float* out = (float*)d_out;

    // workspace: enorm(4KB) | bp1h,bp1l,bp2h (3 x 512KB bf16 packed fragments) | part (8MB)
    float* enorm = (float*)d_ws;
    u16* bp1h = (u16*)(enorm + KK);
    u16* bp1l = bp1h + BPSZ;
    u16* bp2h = bp1l + BPSZ;
    float* part = (float*)(bp2h + BPSZ);
    size_t need = (size_t)KK * sizeof(float) + 3 * (size_t)BPSZ * sizeof(u16)
                + (size_t)NBLK * KK * sizeof(float);
    if (ws_size < need) part = nullptr;

    pack_kernel<<<80, 256, 0, stream>>>(book, lpq, enorm, bp1h, bp1l, bp2h, out);
    gvq_main<<<NBLK, 512, 0, stream>>>(z, lpq, u, enorm, bp1h, bp1l, bp2h, out, part);
    if (part != nullptr)
        meanp_kernel<<<dim3(4, 64), 256, 0, stream>>>(part, out);
}